// Round 10
// baseline (233.013 us; speedup 1.0000x reference)
//
#include <hip/hip_runtime.h>
#include <hip/hip_bf16.h>

// B=8, T=1024, D=512, H=8, DH=64, VS=512
typedef __bf16 bf16;
typedef __bf16 bf16x8 __attribute__((ext_vector_type(8)));
typedef __bf16 bf16x4 __attribute__((ext_vector_type(4)));
typedef float f32x4 __attribute__((ext_vector_type(4)));

#define NEGBIG (-3.0e38f)

__device__ inline f32x4 mfma16(bf16x8 a, bf16x8 b, f32x4 c) {
    return __builtin_amdgcn_mfma_f32_16x16x32_bf16(a, b, c, 0, 0, 0);
}
__device__ inline bf16x8 ld8(const bf16* p) { return *reinterpret_cast<const bf16x8*>(p); }
__device__ inline f32x4 ldf4(const float* p) { return *reinterpret_cast<const f32x4*>(p); }

// DPP row (16-lane) rotate: pure-VALU cross-lane, no LDS round-trip
template<int CTRL>
__device__ inline float rowror(float x) {
    int xi = __builtin_bit_cast(int, x);
    int yi = __builtin_amdgcn_update_dpp(xi, xi, CTRL, 0xF, 0xF, false);
    return __builtin_bit_cast(float, yi);
}
__device__ inline float rowmax16(float x) {
    x = fmaxf(x, rowror<0x121>(x));
    x = fmaxf(x, rowror<0x122>(x));
    x = fmaxf(x, rowror<0x124>(x));
    x = fmaxf(x, rowror<0x128>(x));
    return x;
}
__device__ inline float rowsum16(float x) {
    x += rowror<0x121>(x);
    x += rowror<0x122>(x);
    x += rowror<0x124>(x);
    x += rowror<0x128>(x);
    return x;
}

// ---------------- pe table: fragment-swizzled [l/16][ks][lane][8] ----------------
__global__ void pe_kernel(bf16* __restrict__ pe_b) {
    int l = blockIdx.x, d = threadIdx.x;
    float pos = (float)(l - 1024);
    int k = d & 31;
    float dv = __expf(-(float)k * 0.29710775393471563f);   // ln(10000)/31
    float ang = pos * dv;
    float v = (d < 32) ? sinf(ang) : cosf(ang);
    int idx = (((l >> 4) << 1) + (d >> 5)) * 512 + (((d >> 3) & 3) * 16 + (l & 15)) * 8 + (d & 7);
    pe_b[idx] = (bf16)v;
}

// ---------------- vb table: [8][2048] fp32 ----------------
__global__ void vb_kernel(const float* __restrict__ v_bias, float* __restrict__ vb) {
    int t = blockIdx.x * 256 + threadIdx.x;   // h*2048 + l
    int h = t >> 11, l = t & 2047;
    float pos = (float)(l - 1024);
    float s = 0.f;
    #pragma unroll 4
    for (int d = 0; d < 32; d++) {
        float dv = __expf(-(float)d * 0.29710775393471563f);
        float ang = pos * dv;
        s += v_bias[h * 64 + d] * sinf(ang) + v_bias[h * 64 + 32 + d] * cosf(ang);
    }
    vb[t] = s;
}

// ---------------- key convert: fp32 [b][t][h*64+dh] -> fragment-swizzled bf16 ----------------
__global__ void kcvt_kernel(const float* __restrict__ kin, bf16* __restrict__ kw) {
    int i = (blockIdx.x * 256 + threadIdx.x) * 4;
    f32x4 v = ldf4(kin + i);
    int dh = i & 63, hh = (i >> 6) & 7, t = (i >> 9) & 1023, b = i >> 19;
    int bh = (b << 3) + hh;
    bf16x4 o;
    #pragma unroll
    for (int e = 0; e < 4; e++) o[e] = (bf16)v[e];
    int blk = ((bh << 6) + (t >> 4)) * 2 + (dh >> 5);
    int off = (((dh >> 3) & 3) * 16 + (t & 15)) * 8 + (dh & 7);
    *reinterpret_cast<bf16x4*>(kw + blk * 512 + off) = o;
}

// ---------------- 8192x512x512 GEMM + bias, bf16 MFMA, fp32 accum ----------------
// (measured-best variant: BK=32, fp32 W staged+transposed in-kernel)
// MODE 0: A fp32, out bf16 [((b*8+h)*1024+t)*64+dh]        (q_ws, linear)
// MODE 2: A fp32, out bf16 fragment-swizzled V^T            (v_ws)
// MODE 1: A bf16, out fp32 [row*512+col]                    (d_out)
template<int MODE>
__global__ __launch_bounds__(256) void proj_gemm(const void* __restrict__ Ap, const float* __restrict__ W,
                                                 const float* __restrict__ bias, void* __restrict__ outp) {
    __shared__ bf16 As[64][40];
    __shared__ bf16 Wt[64][40];
    int row0 = blockIdx.x * 64, n0 = blockIdx.y * 64;
    int tid = threadIdx.x, lane = tid & 63, w = tid >> 6, lg = lane >> 4, lr = lane & 15;
    int wm = (w >> 1) * 32, wn = (w & 1) * 32;
    f32x4 acc[2][2] = {};
    for (int k0 = 0; k0 < 512; k0 += 32) {
        int r = tid >> 2, kq = (tid & 3) * 8;
        bf16x8 av;
        if (MODE != 1) {
            const float* A = (const float*)Ap;
            f32x4 a0 = ldf4(A + (row0 + r) * 512 + k0 + kq);
            f32x4 a1 = ldf4(A + (row0 + r) * 512 + k0 + kq + 4);
            #pragma unroll
            for (int e = 0; e < 4; e++) { av[e] = (bf16)a0[e]; av[4 + e] = (bf16)a1[e]; }
        } else {
            av = ld8((const bf16*)Ap + (row0 + r) * 512 + k0 + kq);
        }
        int kk = tid >> 3, n8 = (tid & 7) * 8;
        f32x4 w0 = ldf4(W + (k0 + kk) * 512 + n0 + n8);
        f32x4 w1 = ldf4(W + (k0 + kk) * 512 + n0 + n8 + 4);
        __syncthreads();
        *reinterpret_cast<bf16x8*>(&As[r][kq]) = av;
        #pragma unroll
        for (int e = 0; e < 4; e++) { Wt[n8 + e][kk] = (bf16)w0[e]; Wt[n8 + 4 + e][kk] = (bf16)w1[e]; }
        __syncthreads();
        bf16x8 a0 = ld8(&As[wm + lr][lg * 8]);
        bf16x8 a1 = ld8(&As[wm + 16 + lr][lg * 8]);
        bf16x8 b0 = ld8(&Wt[wn + lr][lg * 8]);
        bf16x8 b1 = ld8(&Wt[wn + 16 + lr][lg * 8]);
        acc[0][0] = mfma16(a0, b0, acc[0][0]);
        acc[0][1] = mfma16(a0, b1, acc[0][1]);
        acc[1][0] = mfma16(a1, b0, acc[1][0]);
        acc[1][1] = mfma16(a1, b1, acc[1][1]);
    }
    #pragma unroll
    for (int mi = 0; mi < 2; mi++)
    #pragma unroll
    for (int ni = 0; ni < 2; ni++) {
        int rowb = row0 + wm + mi * 16 + lg * 4;   // multiple of 4
        int col = n0 + wn + ni * 16 + lr;
        if (MODE == 2) {
            // V^T fragment layout: 4 consecutive t -> contiguous
            int b = rowb >> 10, t = rowb & 1023, hh = col >> 6, dh = col & 63;
            int bh = (b << 3) + hh;
            int blk = (((bh << 4) + (t >> 6)) * 2 + ((t >> 5) & 1)) * 4 + (dh >> 4);
            int off = (((t >> 3) & 3) * 16 + (dh & 15)) * 8 + (t & 7);
            bf16x4 o4;
            #pragma unroll
            for (int rr = 0; rr < 4; rr++) o4[rr] = (bf16)((float)acc[mi][ni][rr] + bias[col]);
            *reinterpret_cast<bf16x4*>((bf16*)outp + blk * 512 + off) = o4;
        } else {
            #pragma unroll
            for (int rr = 0; rr < 4; rr++) {
                int row = rowb + rr;
                float v = (float)acc[mi][ni][rr] + bias[col];
                if (MODE == 0) {
                    int b = row >> 10, t = row & 1023, hh = col >> 6, dh = col & 63;
                    ((bf16*)outp)[((((b << 3) + hh) << 10) + t) * 64 + dh] = (bf16)v;
                } else {
                    ((float*)outp)[row * 512 + col] = v;
                }
            }
        }
    }
}

// ---------------- fused TENER attention: split-j wave pairs, swizzled operands ----------------
// grid (64 bh, 32 qt-pairs), block 256 = 4 waves:
//   wave w -> q-tile (blockIdx.y*2 + (w>>1)), j-half (w&1). Pair merges at end.
// (256,6): raise residency cap 4->6 blocks/CU. VGPR alloc is 56 (cap 84 -> no
// spill); LDS 18.9KB x 6 = 114KB < 160KB.
__global__ __launch_bounds__(256, 6) void tener_attn(const bf16* __restrict__ qw, const bf16* __restrict__ kw,
                                                     const bf16* __restrict__ vt, const int* __restrict__ mask,
                                                     const bf16* __restrict__ peb, const float* __restrict__ vb,
                                                     bf16* __restrict__ xw) {
    __shared__ bf16 Pl[4][16][76];     // per-wave P relayout
    __shared__ float Mo[4][16], Do[4][16];
    __shared__ float Oo[2][16][65];    // odd-wave partial O per pair
    int bh = blockIdx.x, b = bh >> 3, h = bh & 7;
    int tid = threadIdx.x, w = tid >> 6, lane = tid & 63, lg = lane >> 4, lr = lane & 15;
    int rbase = (blockIdx.y * 2 + (w >> 1)) * 16;
    int jh = w & 1;

    const float* vbh  = vb + (h << 11);
    const int* mkb    = mask + (b << 10);

    bf16x8 aq0 = ld8(qw + ((bh << 10) + rbase + lr) * 64 + lg * 8);
    bf16x8 aq1 = ld8(qw + ((bh << 10) + rbase + lr) * 64 + 32 + lg * 8);

    f32x4 o[4] = {};
    float m_[4], d_[4];
    #pragma unroll
    for (int r = 0; r < 4; r++) { m_[r] = NEGBIG; d_[r] = 0.f; }

    for (int tt = 0; tt < 8; tt++) {
        __builtin_amdgcn_sched_barrier(0x7F);   // DS may not cross

        int j0 = jh * 512 + tt * 64;
        int L0 = 1024 + j0 - rbase;

        // S = Q.K^T — fragment loads fully coalesced (base + lane*16B)
        f32x4 s[4];
        int kblk = (bh << 6) + (j0 >> 4);
        #pragma unroll
        for (int nt = 0; nt < 4; nt++) {
            const bf16* kp = kw + (((kblk + nt) << 1)) * 512 + lane * 8;
            f32x4 acc = {};
            acc = mfma16(aq0, ld8(kp), acc);
            acc = mfma16(aq1, ld8(kp + 512), acc);
            s[nt] = acc;
        }

        // R band + vb folded — coalesced pe fragment loads
        f32x4 Rg[5];
        int lb = (L0 - 16) >> 4;
        #pragma unroll
        for (int ut = 0; ut < 5; ut++) {
            const bf16* pp = peb + (((lb + ut) << 1)) * 512 + lane * 8;
            f32x4 acc = {};
            acc = mfma16(aq0, ld8(pp), acc);
            acc = mfma16(aq1, ld8(pp + 512), acc);
            float vbv = vbh[L0 - 16 + ut * 16 + lr];
            #pragma unroll
            for (int r = 0; r < 4; r++) acc[r] += vbv;
            Rg[ut] = acc;
        }

        int mk[4];
        #pragma unroll
        for (int nt = 0; nt < 4; nt++) mk[nt] = mkb[j0 + nt * 16 + lr];

        // online softmax; rel via in-register shuffles, reduces via DPP
        #pragma unroll
        for (int r = 0; r < 4; r++) {
            int rl = 4 * lg + r;
            int dlt = lr - rl;
            int src = (lg << 4) | (dlt & 15);
            float sh[5];
            #pragma unroll
            for (int ut = 0; ut < 5; ut++) sh[ut] = __shfl(Rg[ut][r], src, 64);
            float sv[4];
            #pragma unroll
            for (int nt = 0; nt < 4; nt++) {
                float rel = (dlt >= 0) ? sh[nt + 1] : sh[nt];
                sv[nt] = mk[nt] ? (float)s[nt][r] + rel : NEGBIG;
            }
            float mx = fmaxf(fmaxf(sv[0], sv[1]), fmaxf(sv[2], sv[3]));
            mx = rowmax16(mx);
            float nm = fmaxf(m_[r], mx);
            float sc = __expf(m_[r] - nm);
            float p[4], rs = 0.f;
            #pragma unroll
            for (int nt = 0; nt < 4; nt++) {
                p[nt] = mk[nt] ? __expf(sv[nt] - nm) : 0.f;
                rs += p[nt];
            }
            rs = rowsum16(rs);
            d_[r] = d_[r] * sc + rs;
            m_[r] = nm;
            #pragma unroll
            for (int dt = 0; dt < 4; dt++) o[dt][r] *= sc;
            #pragma unroll
            for (int nt = 0; nt < 4; nt++) Pl[w][rl][nt * 16 + lr] = (bf16)p[nt];
        }

        __builtin_amdgcn_sched_barrier(0x7F);   // DS may not cross (Pl WAR/RAW fence)

        // O += P.V — V^T fragment loads fully coalesced
        int vblk0 = ((((bh << 4) + (j0 >> 6)) << 1)) << 2;
        #pragma unroll
        for (int ks = 0; ks < 2; ks++) {
            bf16x8 ap = ld8(&Pl[w][lr][ks * 32 + lg * 8]);
            #pragma unroll
            for (int dt = 0; dt < 4; dt++) {
                const bf16* vp = vt + (vblk0 + (ks << 2) + dt) * 512 + lane * 8;
                o[dt] = mfma16(ap, ld8(vp), o[dt]);
            }
        }
    }

    // pair-merge: odd wave publishes partials, even wave combines + writes
    if (w & 1) {
        #pragma unroll
        for (int dt = 0; dt < 4; dt++)
        #pragma unroll
        for (int r = 0; r < 4; r++)
            Oo[w >> 1][4 * lg + r][dt * 16 + lr] = o[dt][r];
        if (lr == 0) {
            #pragma unroll
            for (int r = 0; r < 4; r++) { Mo[w][4 * lg + r] = m_[r]; Do[w][4 * lg + r] = d_[r]; }
        }
    }
    __syncthreads();
    if (!(w & 1)) {
        #pragma unroll
        for (int r = 0; r < 4; r++) {
            int rl = 4 * lg + r;
            float m1 = Mo[w | 1][rl], d1 = Do[w | 1][rl];
            float m = fmaxf(m_[r], m1);
            float a0 = __expf(m_[r] - m), a1 = __expf(m1 - m);
            float dd = d_[r] * a0 + d1 * a1;
            float inv = dd > 0.f ? 1.f / dd : 0.f;
            int row = rbase + rl;
            #pragma unroll
            for (int dt = 0; dt < 4; dt++) {
                float v = (o[dt][r] * a0 + Oo[w >> 1][rl][dt * 16 + lr] * a1) * inv;
                xw[(((b << 10) + row) << 9) + (h << 6) + dt * 16 + lr] = (bf16)v;
            }
        }
    }
}

extern "C" void kernel_launch(void* const* d_in, const int* in_sizes, int n_in,
                              void* d_out, int out_size, void* d_ws, size_t ws_size,
                              hipStream_t stream) {
    const float* query  = (const float*)d_in[0];
    const float* key_in = (const float*)d_in[1];
    const float* value  = (const float*)d_in[2];
    const int*   mask   = (const int*)d_in[3];
    const float* Wq     = (const float*)d_in[4];
    const float* bq     = (const float*)d_in[5];
    const float* Wv     = (const float*)d_in[6];
    const float* bv     = (const float*)d_in[7];
    const float* Wo     = (const float*)d_in[8];
    const float* bo     = (const float*)d_in[9];
    const float* v_bias = (const float*)d_in[10];

    char* ws = (char*)d_ws;
    bf16*  pe_b = (bf16*)(ws);                           // 256 KB (swizzled)
    float* vb   = (float*)(ws + 262144);                 // 64 KB
    bf16*  q_ws = (bf16*)(ws + 327680);                  // 8 MB  [bh][t][dh]
    bf16*  v_ws = (bf16*)(ws + 327680 + 8388608);        // 8 MB  V^T fragment-swizzled
    bf16*  x_ws = (bf16*)(ws + 327680 + 16777216);       // 8 MB  [b*t][512]
    // k_ws lives in d_out's first 8 MB; consumed before proj_gemm<1> writes d_out.
    bf16*  k_ws = (bf16*)d_out;

    pe_kernel<<<2048, 64, 0, stream>>>(pe_b);
    vb_kernel<<<64, 256, 0, stream>>>(v_bias, vb);
    kcvt_kernel<<<4096, 256, 0, stream>>>(key_in, k_ws);
    proj_gemm<0><<<dim3(128, 8), 256, 0, stream>>>(query, Wq, bq, q_ws);
    proj_gemm<2><<<dim3(128, 8), 256, 0, stream>>>(value, Wv, bv, v_ws);
    tener_attn<<<dim3(64, 32), 256, 0, stream>>>(q_ws, k_ws, v_ws, mask, pe_b, vb, x_ws);
    proj_gemm<1><<<dim3(128, 8), 256, 0, stream>>>(x_ws, Wo, bo, d_out);
}

// Round 11
// 139.741 us; speedup vs baseline: 1.6675x; 1.6675x over previous
//
#include <hip/hip_runtime.h>
#include <hip/hip_bf16.h>

// B=8, T=1024, D=512, H=8, DH=64, VS=512
typedef __bf16 bf16;
typedef __bf16 bf16x8 __attribute__((ext_vector_type(8)));
typedef __bf16 bf16x4 __attribute__((ext_vector_type(4)));
typedef float f32x4 __attribute__((ext_vector_type(4)));

#define NEGBIG (-3.0e38f)

__device__ inline f32x4 mfma16(bf16x8 a, bf16x8 b, f32x4 c) {
    return __builtin_amdgcn_mfma_f32_16x16x32_bf16(a, b, c, 0, 0, 0);
}
__device__ inline bf16x8 ld8(const bf16* p) { return *reinterpret_cast<const bf16x8*>(p); }
__device__ inline f32x4 ldf4(const float* p) { return *reinterpret_cast<const f32x4*>(p); }

// DPP row (16-lane) rotate: pure-VALU cross-lane, no LDS round-trip
template<int CTRL>
__device__ inline float rowror(float x) {
    int xi = __builtin_bit_cast(int, x);
    int yi = __builtin_amdgcn_update_dpp(xi, xi, CTRL, 0xF, 0xF, false);
    return __builtin_bit_cast(float, yi);
}
__device__ inline float rowmax16(float x) {
    x = fmaxf(x, rowror<0x121>(x));
    x = fmaxf(x, rowror<0x122>(x));
    x = fmaxf(x, rowror<0x124>(x));
    x = fmaxf(x, rowror<0x128>(x));
    return x;
}
__device__ inline float rowsum16(float x) {
    x += rowror<0x121>(x);
    x += rowror<0x122>(x);
    x += rowror<0x124>(x);
    x += rowror<0x128>(x);
    return x;
}

// ---------------- pe table: fragment-swizzled [l/16][ks][lane][8] ----------------
__global__ void pe_kernel(bf16* __restrict__ pe_b) {
    int l = blockIdx.x, d = threadIdx.x;
    float pos = (float)(l - 1024);
    int k = d & 31;
    float dv = __expf(-(float)k * 0.29710775393471563f);   // ln(10000)/31
    float ang = pos * dv;
    float v = (d < 32) ? sinf(ang) : cosf(ang);
    int idx = (((l >> 4) << 1) + (d >> 5)) * 512 + (((d >> 3) & 3) * 16 + (l & 15)) * 8 + (d & 7);
    pe_b[idx] = (bf16)v;
}

// ---------------- vb table: [8][2048] fp32 ----------------
__global__ void vb_kernel(const float* __restrict__ v_bias, float* __restrict__ vb) {
    int t = blockIdx.x * 256 + threadIdx.x;   // h*2048 + l
    int h = t >> 11, l = t & 2047;
    float pos = (float)(l - 1024);
    float s = 0.f;
    #pragma unroll 4
    for (int d = 0; d < 32; d++) {
        float dv = __expf(-(float)d * 0.29710775393471563f);
        float ang = pos * dv;
        s += v_bias[h * 64 + d] * sinf(ang) + v_bias[h * 64 + 32 + d] * cosf(ang);
    }
    vb[t] = s;
}

// ---------------- key convert: fp32 [b][t][h*64+dh] -> fragment-swizzled bf16 ----------------
__global__ void kcvt_kernel(const float* __restrict__ kin, bf16* __restrict__ kw) {
    int i = (blockIdx.x * 256 + threadIdx.x) * 4;
    f32x4 v = ldf4(kin + i);
    int dh = i & 63, hh = (i >> 6) & 7, t = (i >> 9) & 1023, b = i >> 19;
    int bh = (b << 3) + hh;
    bf16x4 o;
    #pragma unroll
    for (int e = 0; e < 4; e++) o[e] = (bf16)v[e];
    int blk = ((bh << 6) + (t >> 4)) * 2 + (dh >> 5);
    int off = (((dh >> 3) & 3) * 16 + (t & 15)) * 8 + (dh & 7);
    *reinterpret_cast<bf16x4*>(kw + blk * 512 + off) = o;
}

// ---------------- weight transpose+convert x3 in one launch: W[k][n] fp32 -> Wt[n][k] bf16 ----------------
__global__ __launch_bounds__(256) void wcvt_kernel(const float* __restrict__ W0, const float* __restrict__ W1,
                                                   const float* __restrict__ W2, bf16* __restrict__ T0,
                                                   bf16* __restrict__ T1, bf16* __restrict__ T2) {
    __shared__ float tile[64][65];
    int which = blockIdx.x >> 6, bidx = blockIdx.x & 63;
    const float* W = which == 0 ? W0 : which == 1 ? W1 : W2;
    bf16* Wt = which == 0 ? T0 : which == 1 ? T1 : T2;
    int tx = bidx & 7, ty = bidx >> 3;    // tile n-col, k-row
    int lane = threadIdx.x & 63, w = threadIdx.x >> 6;
    #pragma unroll
    for (int i = 0; i < 16; i++) {
        int k = ty * 64 + w * 16 + i;
        tile[w * 16 + i][lane] = W[k * 512 + tx * 64 + lane];
    }
    __syncthreads();
    #pragma unroll
    for (int i = 0; i < 16; i++) {
        int n = tx * 64 + w * 16 + i;
        Wt[n * 512 + ty * 64 + lane] = (bf16)tile[lane][w * 16 + i];
    }
}

// ---------------- proj GEMM: measured-best 64x64/BK32 structure, pre-transposed bf16 W ----------------
// MODE 0: A fp32, out bf16 [((b*8+h)*1024+t)*64+dh]        (q_ws, linear)
// MODE 2: A fp32, out bf16 fragment-swizzled V^T            (v_ws)
// MODE 1: A bf16, out fp32 [row*512+col]                    (d_out)
template<int MODE>
__global__ __launch_bounds__(256) void proj_gemm(const void* __restrict__ Ap, const bf16* __restrict__ Wt,
                                                 const float* __restrict__ bias, void* __restrict__ outp) {
    __shared__ bf16 As[64][40];
    __shared__ bf16 Bs[64][40];   // [n][k]
    int row0 = blockIdx.x * 64, n0 = blockIdx.y * 64;
    int tid = threadIdx.x, lane = tid & 63, w = tid >> 6, lg = lane >> 4, lr = lane & 15;
    int wm = (w >> 1) * 32, wn = (w & 1) * 32;
    f32x4 acc[2][2] = {};
    for (int k0 = 0; k0 < 512; k0 += 32) {
        int r = tid >> 2, kq = (tid & 3) * 8;
        bf16x8 av;
        if (MODE != 1) {
            const float* A = (const float*)Ap;
            f32x4 a0 = ldf4(A + (row0 + r) * 512 + k0 + kq);
            f32x4 a1 = ldf4(A + (row0 + r) * 512 + k0 + kq + 4);
            #pragma unroll
            for (int e = 0; e < 4; e++) { av[e] = (bf16)a0[e]; av[4 + e] = (bf16)a1[e]; }
        } else {
            av = ld8((const bf16*)Ap + (row0 + r) * 512 + k0 + kq);
        }
        bf16x8 bv = ld8(Wt + (n0 + r) * 512 + k0 + kq);   // pre-transposed: same pattern as A
        __syncthreads();
        *reinterpret_cast<bf16x8*>(&As[r][kq]) = av;
        *reinterpret_cast<bf16x8*>(&Bs[r][kq]) = bv;
        __syncthreads();
        bf16x8 a0 = ld8(&As[wm + lr][lg * 8]);
        bf16x8 a1 = ld8(&As[wm + 16 + lr][lg * 8]);
        bf16x8 b0 = ld8(&Bs[wn + lr][lg * 8]);
        bf16x8 b1 = ld8(&Bs[wn + 16 + lr][lg * 8]);
        acc[0][0] = mfma16(a0, b0, acc[0][0]);
        acc[0][1] = mfma16(a0, b1, acc[0][1]);
        acc[1][0] = mfma16(a1, b0, acc[1][0]);
        acc[1][1] = mfma16(a1, b1, acc[1][1]);
    }
    #pragma unroll
    for (int mi = 0; mi < 2; mi++)
    #pragma unroll
    for (int ni = 0; ni < 2; ni++) {
        int rowb = row0 + wm + mi * 16 + lg * 4;   // multiple of 4
        int col = n0 + wn + ni * 16 + lr;
        if (MODE == 2) {
            // V^T fragment layout: 4 consecutive t -> contiguous
            int b = rowb >> 10, t = rowb & 1023, hh = col >> 6, dh = col & 63;
            int bh = (b << 3) + hh;
            int blk = (((bh << 4) + (t >> 6)) * 2 + ((t >> 5) & 1)) * 4 + (dh >> 4);
            int off = (((t >> 3) & 3) * 16 + (dh & 15)) * 8 + (t & 7);
            bf16x4 o4;
            #pragma unroll
            for (int rr = 0; rr < 4; rr++) o4[rr] = (bf16)((float)acc[mi][ni][rr] + bias[col]);
            *reinterpret_cast<bf16x4*>((bf16*)outp + blk * 512 + off) = o4;
        } else {
            #pragma unroll
            for (int rr = 0; rr < 4; rr++) {
                int row = rowb + rr;
                float v = (float)acc[mi][ni][rr] + bias[col];
                if (MODE == 0) {
                    int b = row >> 10, t = row & 1023, hh = col >> 6, dh = col & 63;
                    ((bf16*)outp)[((((b << 3) + hh) << 10) + t) * 64 + dh] = (bf16)v;
                } else {
                    ((float*)outp)[row * 512 + col] = v;
                }
            }
        }
    }
}

// ---------------- fused TENER attention: split-j wave pairs, swizzled operands ----------------
// grid (64 bh, 32 qt-pairs), block 256 = 4 waves:
//   wave w -> q-tile (blockIdx.y*2 + (w>>1)), j-half (w&1). Pair merges at end.
// (256,4) is the measured-best: VGPR 56, no spill. (256,6)/(256,8) both spill
// (r5: 860MB, r10: 300MB scratch traffic). Do not tighten.
__global__ __launch_bounds__(256, 4) void tener_attn(const bf16* __restrict__ qw, const bf16* __restrict__ kw,
                                                     const bf16* __restrict__ vt, const int* __restrict__ mask,
                                                     const bf16* __restrict__ peb, const float* __restrict__ vb,
                                                     bf16* __restrict__ xw) {
    __shared__ bf16 Pl[4][16][76];     // per-wave P relayout
    __shared__ float Mo[4][16], Do[4][16];
    __shared__ float Oo[2][16][65];    // odd-wave partial O per pair
    int bh = blockIdx.x, b = bh >> 3, h = bh & 7;
    int tid = threadIdx.x, w = tid >> 6, lane = tid & 63, lg = lane >> 4, lr = lane & 15;
    int rbase = (blockIdx.y * 2 + (w >> 1)) * 16;
    int jh = w & 1;

    const float* vbh  = vb + (h << 11);
    const int* mkb    = mask + (b << 10);

    bf16x8 aq0 = ld8(qw + ((bh << 10) + rbase + lr) * 64 + lg * 8);
    bf16x8 aq1 = ld8(qw + ((bh << 10) + rbase + lr) * 64 + 32 + lg * 8);

    f32x4 o[4] = {};
    float m_[4], d_[4];
    #pragma unroll
    for (int r = 0; r < 4; r++) { m_[r] = NEGBIG; d_[r] = 0.f; }

    for (int tt = 0; tt < 8; tt++) {
        __builtin_amdgcn_sched_barrier(0x7F);   // DS may not cross

        int j0 = jh * 512 + tt * 64;
        int L0 = 1024 + j0 - rbase;

        // S = Q.K^T — fragment loads fully coalesced (base + lane*16B)
        f32x4 s[4];
        int kblk = (bh << 6) + (j0 >> 4);
        #pragma unroll
        for (int nt = 0; nt < 4; nt++) {
            const bf16* kp = kw + (((kblk + nt) << 1)) * 512 + lane * 8;
            f32x4 acc = {};
            acc = mfma16(aq0, ld8(kp), acc);
            acc = mfma16(aq1, ld8(kp + 512), acc);
            s[nt] = acc;
        }

        // R band + vb folded — coalesced pe fragment loads
        f32x4 Rg[5];
        int lb = (L0 - 16) >> 4;
        #pragma unroll
        for (int ut = 0; ut < 5; ut++) {
            const bf16* pp = peb + (((lb + ut) << 1)) * 512 + lane * 8;
            f32x4 acc = {};
            acc = mfma16(aq0, ld8(pp), acc);
            acc = mfma16(aq1, ld8(pp + 512), acc);
            float vbv = vbh[L0 - 16 + ut * 16 + lr];
            #pragma unroll
            for (int r = 0; r < 4; r++) acc[r] += vbv;
            Rg[ut] = acc;
        }

        int mk[4];
        #pragma unroll
        for (int nt = 0; nt < 4; nt++) mk[nt] = mkb[j0 + nt * 16 + lr];

        // online softmax; rel via in-register shuffles, reduces via DPP
        #pragma unroll
        for (int r = 0; r < 4; r++) {
            int rl = 4 * lg + r;
            int dlt = lr - rl;
            int src = (lg << 4) | (dlt & 15);
            float sh[5];
            #pragma unroll
            for (int ut = 0; ut < 5; ut++) sh[ut] = __shfl(Rg[ut][r], src, 64);
            float sv[4];
            #pragma unroll
            for (int nt = 0; nt < 4; nt++) {
                float rel = (dlt >= 0) ? sh[nt + 1] : sh[nt];
                sv[nt] = mk[nt] ? (float)s[nt][r] + rel : NEGBIG;
            }
            float mx = fmaxf(fmaxf(sv[0], sv[1]), fmaxf(sv[2], sv[3]));
            mx = rowmax16(mx);
            float nm = fmaxf(m_[r], mx);
            float sc = __expf(m_[r] - nm);
            float p[4], rs = 0.f;
            #pragma unroll
            for (int nt = 0; nt < 4; nt++) {
                p[nt] = mk[nt] ? __expf(sv[nt] - nm) : 0.f;
                rs += p[nt];
            }
            rs = rowsum16(rs);
            d_[r] = d_[r] * sc + rs;
            m_[r] = nm;
            #pragma unroll
            for (int dt = 0; dt < 4; dt++) o[dt][r] *= sc;
            #pragma unroll
            for (int nt = 0; nt < 4; nt++) Pl[w][rl][nt * 16 + lr] = (bf16)p[nt];
        }

        __builtin_amdgcn_sched_barrier(0x7F);   // DS may not cross (Pl WAR/RAW fence)

        // O += P.V — V^T fragment loads fully coalesced
        int vblk0 = ((((bh << 4) + (j0 >> 6)) << 1)) << 2;
        #pragma unroll
        for (int ks = 0; ks < 2; ks++) {
            bf16x8 ap = ld8(&Pl[w][lr][ks * 32 + lg * 8]);
            #pragma unroll
            for (int dt = 0; dt < 4; dt++) {
                const bf16* vp = vt + (vblk0 + (ks << 2) + dt) * 512 + lane * 8;
                o[dt] = mfma16(ap, ld8(vp), o[dt]);
            }
        }
    }

    // pair-merge: odd wave publishes partials, even wave combines + writes
    if (w & 1) {
        #pragma unroll
        for (int dt = 0; dt < 4; dt++)
        #pragma unroll
        for (int r = 0; r < 4; r++)
            Oo[w >> 1][4 * lg + r][dt * 16 + lr] = o[dt][r];
        if (lr == 0) {
            #pragma unroll
            for (int r = 0; r < 4; r++) { Mo[w][4 * lg + r] = m_[r]; Do[w][4 * lg + r] = d_[r]; }
        }
    }
    __syncthreads();
    if (!(w & 1)) {
        #pragma unroll
        for (int r = 0; r < 4; r++) {
            int rl = 4 * lg + r;
            float m1 = Mo[w | 1][rl], d1 = Do[w | 1][rl];
            float m = fmaxf(m_[r], m1);
            float a0 = __expf(m_[r] - m), a1 = __expf(m1 - m);
            float dd = d_[r] * a0 + d1 * a1;
            float inv = dd > 0.f ? 1.f / dd : 0.f;
            int row = rbase + rl;
            #pragma unroll
            for (int dt = 0; dt < 4; dt++) {
                float v = (o[dt][r] * a0 + Oo[w >> 1][rl][dt * 16 + lr] * a1) * inv;
                xw[(((b << 10) + row) << 9) + (h << 6) + dt * 16 + lr] = (bf16)v;
            }
        }
    }
}

extern "C" void kernel_launch(void* const* d_in, const int* in_sizes, int n_in,
                              void* d_out, int out_size, void* d_ws, size_t ws_size,
                              hipStream_t stream) {
    const float* query  = (const float*)d_in[0];
    const float* key_in = (const float*)d_in[1];
    const float* value  = (const float*)d_in[2];
    const int*   mask   = (const int*)d_in[3];
    const float* Wq     = (const float*)d_in[4];
    const float* bq     = (const float*)d_in[5];
    const float* Wv     = (const float*)d_in[6];
    const float* bv     = (const float*)d_in[7];
    const float* Wo     = (const float*)d_in[8];
    const float* bo     = (const float*)d_in[9];
    const float* v_bias = (const float*)d_in[10];

    char* ws = (char*)d_ws;
    bf16*  pe_b = (bf16*)(ws);                           // 256 KB (swizzled)
    float* vb   = (float*)(ws + 262144);                 // 64 KB
    bf16*  q_ws = (bf16*)(ws + 327680);                  // 8 MB  [bh][t][dh]
    bf16*  v_ws = (bf16*)(ws + 327680 + 8388608);        // 8 MB  V^T fragment-swizzled
    bf16*  x_ws = (bf16*)(ws + 327680 + 16777216);       // 8 MB  [b*t][512]
    bf16*  wt_q = (bf16*)(ws + 327680 + 25165824);       // 512 KB  Wq^T bf16
    bf16*  wt_v = (bf16*)(ws + 327680 + 25690112);       // 512 KB  Wv^T bf16
    bf16*  wt_o = (bf16*)(ws + 327680 + 26214400);       // 512 KB  Wo^T bf16
    // k_ws lives in d_out's first 8 MB; consumed before proj_gemm<1> writes d_out.
    bf16*  k_ws = (bf16*)d_out;

    pe_kernel<<<2048, 64, 0, stream>>>(pe_b);
    vb_kernel<<<64, 256, 0, stream>>>(v_bias, vb);
    kcvt_kernel<<<4096, 256, 0, stream>>>(key_in, k_ws);
    wcvt_kernel<<<192, 256, 0, stream>>>(Wq, Wv, Wo, wt_q, wt_v, wt_o);
    proj_gemm<0><<<dim3(128, 8), 256, 0, stream>>>(query, wt_q, bq, q_ws);
    proj_gemm<2><<<dim3(128, 8), 256, 0, stream>>>(value, wt_v, bv, v_ws);
    tener_attn<<<dim3(64, 32), 256, 0, stream>>>(q_ws, k_ws, v_ws, mask, pe_b, vb, x_ws);
    proj_gemm<1><<<dim3(128, 8), 256, 0, stream>>>(x_ws, wt_o, bo, d_out);
}